// Round 2
// baseline (233.766 us; speedup 1.0000x reference)
//
#include <hip/hip_runtime.h>
#include <math.h>

#define BB 4
#define HH 8
#define NN 2048
#define DD 64
#define KTOP 16
#define CUT_MARGIN 1e-3f

typedef _Float16 half_t;
typedef __attribute__((ext_vector_type(8))) _Float16 half8;
typedef __attribute__((ext_vector_type(4))) float floatx4;

// async 16B global->LDS copy (hardware scatters lane i at ldsbase + i*16)
__device__ __forceinline__ void gl_lds16(const half_t* g, half_t* l) {
    __builtin_amdgcn_global_load_lds(
        (const __attribute__((address_space(1))) void*)g,
        (__attribute__((address_space(3))) void*)l, 16, 0, 0);
}

// ---------------------------------------------------------------------------
// Kernel 0: split fp32 q,k into f16 hi + f16 (lo*2^11), PLAIN row-major.
// (swizzle removed: gemm now gather-stages, so global layout is linear)
// ---------------------------------------------------------------------------
__global__ __launch_bounds__(256) void split_plain(const float* __restrict__ q,
                                                   const float* __restrict__ kk,
                                                   half_t* __restrict__ qhi,
                                                   half_t* __restrict__ qlo,
                                                   half_t* __restrict__ khi,
                                                   half_t* __restrict__ klo) {
    const int uidx = blockIdx.x * 256 + threadIdx.x;  // 16B-unit index
    const size_t src = (size_t)uidx * 8;

    float a[8], b[8];
    *(float4*)&a[0] = *(const float4*)(q + src);
    *(float4*)&a[4] = *(const float4*)(q + src + 4);
    *(float4*)&b[0] = *(const float4*)(kk + src);
    *(float4*)&b[4] = *(const float4*)(kk + src + 4);
    half8 qh, ql, kh, kl;
#pragma unroll
    for (int e = 0; e < 8; ++e) {
        half_t hq = (half_t)a[e];
        half_t hk = (half_t)b[e];
        qh[e] = hq; ql[e] = (half_t)((a[e] - (float)hq) * 2048.0f);
        kh[e] = hk; kl[e] = (half_t)((b[e] - (float)hk) * 2048.0f);
    }
    *(half8*)(qhi + src) = qh;
    *(half8*)(qlo + src) = ql;
    *(half8*)(khi + src) = kh;
    *(half8*)(klo + src) = kl;
}

// ---------------------------------------------------------------------------
// Kernel 1 (v2): L = (1/64) * sum_{h,d} q.k via f16x3 MFMA (16x16x32_f16).
// 2-phase prefetch pipeline: 16 half-head steps (BK=32), double-buffered
// LDS (still 64 KB total -> 2 blocks/CU). Stage(next) issued BEFORE
// compute(cur); single __syncthreads per step puts the vmcnt(0) drain
// AFTER ~500 cyc of MFMA instead of before it.
//
// Gather-staging: global_load_lds writes LDS linearly (lane*16B); each lane
// picks its (row, k-group). LDS layout phys(r,t) = (r>>3)*256 + t*64 + (r&7)*8
// halfs  ==> frag ds_read_b128 is bank-conflict-free per quarter-wave phase
// (8 slots x 2 lanes). Fragment semantics (k = (s&1)*32 + quad*8) identical
// to v1's unit = ks*4+quad.
// ---------------------------------------------------------------------------
__global__ __launch_bounds__(256, 2) void gemm_f16x3(const half_t* __restrict__ qhi,
                                                     const half_t* __restrict__ qlo,
                                                     const half_t* __restrict__ khi,
                                                     const half_t* __restrict__ klo,
                                                     float* __restrict__ L) {
    const int b  = blockIdx.z;
    const int i0 = blockIdx.y * 128;
    const int j0 = blockIdx.x * 128;
    const int tid  = threadIdx.x;
    const int wave = __builtin_amdgcn_readfirstlane(tid >> 6);
    const int lane = tid & 63;
    const int wr = wave >> 1, wc = wave & 1;
    const int lm = lane & 15, quad = lane >> 4;

    // 4 matrices x 2 buffers x (128 rows x 32 halfs) = 64 KB
    __shared__ __align__(16) half_t Ah[2][4096];
    __shared__ __align__(16) half_t Al[2][4096];
    __shared__ __align__(16) half_t Bh[2][4096];
    __shared__ __align__(16) half_t Bl[2][4096];

    // gather-staging decode: call i, lane L writes phys unit i*64+L;
    // that unit holds (row = i*16 + (L>>5)*8 + (L&7), kgroup t = (L>>3)&3)
    const int r_base = ((lane >> 5) << 3) + (lane & 7);
    const int t_l    = (lane >> 3) & 3;

    const half_t* gmat;
    half_t* lmat;
    int rowoff;
    if      (wave == 0) { gmat = qhi; lmat = &Ah[0][0]; rowoff = i0; }
    else if (wave == 1) { gmat = qlo; lmat = &Al[0][0]; rowoff = i0; }
    else if (wave == 2) { gmat = khi; lmat = &Bh[0][0]; rowoff = j0; }
    else                { gmat = klo; lmat = &Bl[0][0]; rowoff = j0; }
    const half_t* glane = gmat + ((size_t)b * HH * NN + rowoff + r_base) * DD + t_l * 8;

#define STAGE(s, bufidx)                                                      \
    {                                                                         \
        const half_t* gs = glane + (size_t)((s) >> 1) * (NN * DD) + ((s)&1) * 32; \
        half_t* ls = lmat + (bufidx)*4096;                                    \
        _Pragma("unroll") for (int i = 0; i < 8; ++i)                         \
            gl_lds16(gs + i * 1024, ls + i * 512);                            \
    }

    floatx4 acc1[4][4], acc2[4][4];
#pragma unroll
    for (int tr = 0; tr < 4; ++tr)
#pragma unroll
        for (int tc = 0; tc < 4; ++tc) {
            acc1[tr][tc] = (floatx4)0.0f;
            acc2[tr][tc] = (floatx4)0.0f;
        }

#define COMPUTE(bufidx)                                                       \
    {                                                                         \
        half8 ah[4], al[4], bh[4], bl[4];                                     \
        _Pragma("unroll") for (int t = 0; t < 4; ++t) {                       \
            const int am = wr * 64 + t * 16 + lm;                             \
            const int bm = wc * 64 + t * 16 + lm;                             \
            const int ai = ((am >> 3) << 8) + (quad << 6) + ((am & 7) << 3);  \
            const int bi = ((bm >> 3) << 8) + (quad << 6) + ((bm & 7) << 3);  \
            ah[t] = *(const half8*)&Ah[bufidx][ai];                           \
            al[t] = *(const half8*)&Al[bufidx][ai];                           \
            bh[t] = *(const half8*)&Bh[bufidx][bi];                           \
            bl[t] = *(const half8*)&Bl[bufidx][bi];                           \
        }                                                                     \
        __builtin_amdgcn_s_setprio(1);                                        \
        _Pragma("unroll") for (int tr = 0; tr < 4; ++tr)                      \
            _Pragma("unroll") for (int tc = 0; tc < 4; ++tc) {                \
                acc1[tr][tc] = __builtin_amdgcn_mfma_f32_16x16x32_f16(        \
                    ah[tr], bh[tc], acc1[tr][tc], 0, 0, 0);                   \
                acc2[tr][tc] = __builtin_amdgcn_mfma_f32_16x16x32_f16(        \
                    ah[tr], bl[tc], acc2[tr][tc], 0, 0, 0);                   \
                acc2[tr][tc] = __builtin_amdgcn_mfma_f32_16x16x32_f16(        \
                    al[tr], bh[tc], acc2[tr][tc], 0, 0, 0);                   \
            }                                                                 \
        __builtin_amdgcn_s_setprio(0);                                        \
    }

    // ---- pipelined loop over 16 half-head steps ----
    STAGE(0, 0);
    __syncthreads();
#pragma unroll
    for (int ss = 0; ss < 7; ++ss) {
        STAGE(2 * ss + 1, 1);
        COMPUTE(0);
        __syncthreads();
        STAGE(2 * ss + 2, 0);
        COMPUTE(1);
        __syncthreads();
    }
    STAGE(15, 1);
    COMPUTE(0);
    __syncthreads();
    COMPUTE(1);

#undef STAGE
#undef COMPUTE

    const float s1 = 0.015625f;
    const float s2 = 0.015625f / 2048.0f;
#pragma unroll
    for (int tr = 0; tr < 4; ++tr)
#pragma unroll
        for (int r = 0; r < 4; ++r) {
            const int grow = i0 + wr * 64 + tr * 16 + quad * 4 + r;
            float* Lp = L + ((size_t)b * NN + grow) * NN + j0 + wc * 64 + lm;
#pragma unroll
            for (int tc = 0; tc < 4; ++tc)
                Lp[tc * 16] = acc1[tr][tc][r] * s1 + acc2[tr][tc][r] * s2;
        }
}

// ---------------------------------------------------------------------------
// Kernel 2: one wave per row (unchanged — passed with absmax 0.0).
// ---------------------------------------------------------------------------
__device__ __forceinline__ unsigned long long flip64(double x) {
    unsigned long long v = (unsigned long long)__double_as_longlong(x);
    return v ^ ((0ULL - (v >> 63)) | 0x8000000000000000ULL);
}
__device__ __forceinline__ double unflip64(unsigned long long k) {
    unsigned long long v = (k >> 63) ? (k ^ 0x8000000000000000ULL) : ~k;
    return __longlong_as_double((long long)v);
}

__global__ __launch_bounds__(64) void topk_mask(float* __restrict__ LM,
                                                const float* __restrict__ u) {
    const int row  = blockIdx.x;
    const int lane = threadIdx.x;          // 0..63, one wave
    float* lrow = LM + (size_t)row * NN;
    const float* urow = u + (size_t)row * NN;

    __shared__ int s_idx[64];

    // ---- phase A: stream row, keep only z + hard bitmask ----
    float z[32];
    unsigned hard = 0;
    float4 lb = *(const float4*)(lrow + lane * 4);
    float4 ub = *(const float4*)(urow + lane * 4);
#pragma unroll
    for (int e = 0; e < 8; ++e) {
        float4 lnx, unx;
        if (e < 7) {
            lnx = *(const float4*)(lrow + (e + 1) * 256 + lane * 4);
            unx = *(const float4*)(urow + (e + 1) * 256 + lane * 4);
        }
        const float* ls = (const float*)&lb;
        const float* us = (const float*)&ub;
#pragma unroll
        for (int s = 0; s < 4; ++s) {
            float w = -__logf(us[s] + 1e-9f);
            z[e * 4 + s] = ls[s] - __logf(w + 1e-9f);
            hard |= (us[s] > 0.999f ? 1u : 0u) << (e * 4 + s);
        }
        lb = lnx; ub = unx;
    }

    // ---- phase B: cutoff = (16th largest of 64 lane-maxima) - margin ----
    float v = z[0];
#pragma unroll
    for (int r = 1; r < 32; ++r) v = fmaxf(v, z[r]);
#pragma unroll
    for (int kS = 2; kS <= 64; kS <<= 1) {
#pragma unroll
        for (int j = kS >> 1; j > 0; j >>= 1) {
            float o = __shfl_xor(v, j, 64);
            bool asc = ((lane & kS) == 0);
            bool lower = ((lane & j) == 0);
            float mn = fminf(v, o), mx = fmaxf(v, o);
            v = (asc == lower) ? mn : mx;
        }
    }
    const float cut = __shfl(v, 48, 64) - CUT_MARGIN;

    // ---- phase C: ballot-prefix candidate gather (indices only) ----
    int c = 0;
#pragma unroll
    for (int r = 0; r < 32; ++r) {
        bool p = (z[r] >= cut);
        unsigned long long m = __ballot(p);
        if (p) {
            int slot = c + __popcll(m & ((1ULL << lane) - 1ULL));
            if (slot < 64) s_idx[slot] = (r >> 2) * 256 + lane * 4 + (r & 3);
        }
        c += __popcll(m);
    }
    if (c > 64) c = 64;

    // ---- phase D: f64 keys; fixed 64-wide bitonic sort (ascending);
    //      threshold = sorted lane c-16 (exact 16th-largest z64) ----
    unsigned long long key = 0xFFFFFFFFFFFFFFFFULL;
    if (lane < c) {
        int idx = s_idx[lane];
        double uu = (double)urow[idx] + 1e-9;   // cache-hot gather
        double w  = -log(uu);
        double g  = -log(w + 1e-9);
        key = flip64((double)lrow[idx] + g);
    }
#pragma unroll
    for (int kS = 2; kS <= 64; kS <<= 1) {
#pragma unroll
        for (int j = kS >> 1; j > 0; j >>= 1) {
            unsigned long long o = __shfl_xor(key, j, 64);
            bool asc = ((lane & kS) == 0);
            bool lower = ((lane & j) == 0);
            unsigned long long mn = (key < o) ? key : o;
            unsigned long long mx = (key < o) ? o : key;
            key = (asc == lower) ? mn : mx;
        }
    }
    const double thresh = unflip64(__shfl(key, c - KTOP, 64));

    // ---- phase E0: band|hard elements resolved in f64 ONCE, patch z ----
    const float t_hi = (float)thresh + 3e-4f;
    const float t_lo = (float)thresh - 3e-4f;
    unsigned bm = hard;
#pragma unroll
    for (int r = 0; r < 32; ++r)
        bm |= ((z[r] <= t_hi && z[r] >= t_lo) ? 1u : 0u) << r;
    while (bm) {           // expected ~0-2 iterations per wave, sparse exec
        int t = __builtin_ctz(bm);
        bm &= bm - 1;
        const int idx = (t >> 2) * 256 + lane * 4 + (t & 3);
        double uu = (double)urow[idx] + 1e-9;
        double w  = -log(uu);
        double g  = -log(w + 1e-9);
        double z64 = (double)lrow[idx] + g;    // L still intact (no stores yet)
        z[t] = (z64 >= thresh) ? 1.0e30f : -1.0e30f;
    }

    // ---- phase E1: pure-f32 store pass ----
#pragma unroll
    for (int e = 0; e < 8; ++e) {
        float o[4];
#pragma unroll
        for (int s = 0; s < 4; ++s)
            o[s] = (z[e * 4 + s] > t_hi) ? 1.0f : 0.0f;
        *(float4*)(lrow + e * 256 + lane * 4) = *(float4*)o;
    }
}

extern "C" void kernel_launch(void* const* d_in, const int* in_sizes, int n_in,
                              void* d_out, int out_size, void* d_ws, size_t ws_size,
                              hipStream_t stream) {
    const float* q = (const float*)d_in[0];
    const float* k = (const float*)d_in[1];
    const float* u = (const float*)d_in[2];
    float* out = (float*)d_out;          // logits scratch, then final mask
    const size_t NQ = (size_t)BB * HH * NN * DD;   // 4M elements
    half_t* qhi = (half_t*)d_ws;
    half_t* qlo = qhi + NQ;
    half_t* khi = qlo + NQ;
    half_t* klo = khi + NQ;              // 32 MB total in d_ws

    split_plain<<<(int)(NQ / 8 / 256), 256, 0, stream>>>(q, k, qhi, qlo, khi, klo);

    dim3 grid1(NN / 128, NN / 128, BB);
    gemm_f16x3<<<grid1, 256, 0, stream>>>(qhi, qlo, khi, klo, out);

    topk_mask<<<BB * NN, 64, 0, stream>>>(out, u);
}

// Round 3
// 221.554 us; speedup vs baseline: 1.0551x; 1.0551x over previous
//
#include <hip/hip_runtime.h>
#include <math.h>

#define BB 4
#define HH 8
#define NN 2048
#define DD 64
#define KTOP 16
#define CUT_MARGIN 1e-3f

typedef _Float16 half_t;
typedef __attribute__((ext_vector_type(8))) _Float16 half8;
typedef __attribute__((ext_vector_type(4))) float floatx4;

// async 16B global->LDS copy (hardware scatters lane i at ldsbase + i*16)
__device__ __forceinline__ void gl_lds16(const half_t* g, half_t* l) {
    __builtin_amdgcn_global_load_lds(
        (const __attribute__((address_space(1))) void*)g,
        (__attribute__((address_space(3))) void*)l, 16, 0, 0);
}

// ---------------------------------------------------------------------------
// Kernel 0: split fp32 q,k into f16 hi + f16 (lo*2^11), K-BLOCKED layout
// [B][H][2][N][32]: element (b,h,n,d) -> plane (b*H+h)*2 + d/32, row n,
// col d%32. A BK=32 gemm tile is then 8KB fully contiguous.
// ---------------------------------------------------------------------------
__global__ __launch_bounds__(256) void split_kblock(const float* __restrict__ q,
                                                    const float* __restrict__ kk,
                                                    half_t* __restrict__ qhi,
                                                    half_t* __restrict__ qlo,
                                                    half_t* __restrict__ khi,
                                                    half_t* __restrict__ klo) {
    const int uidx = blockIdx.x * 256 + threadIdx.x;  // 16B-unit index
    const size_t src = (size_t)uidx * 8;
    const int R  = uidx >> 3;           // global row over B*H*N
    const int kg = uidx & 7;            // 8-half group within the 64-row
    const int bh = R >> 11;             // b*H + h   (N = 2048)
    const int n  = R & 2047;
    const size_t dst = (((size_t)(bh * 2 + (kg >> 2)) << 11) + n) * 32 + (kg & 3) * 8;

    float a[8], b[8];
    *(float4*)&a[0] = *(const float4*)(q + src);
    *(float4*)&a[4] = *(const float4*)(q + src + 4);
    *(float4*)&b[0] = *(const float4*)(kk + src);
    *(float4*)&b[4] = *(const float4*)(kk + src + 4);
    half8 qh, ql, kh, kl;
#pragma unroll
    for (int e = 0; e < 8; ++e) {
        half_t hq = (half_t)a[e];
        half_t hk = (half_t)b[e];
        qh[e] = hq; ql[e] = (half_t)((a[e] - (float)hq) * 2048.0f);
        kh[e] = hk; kl[e] = (half_t)((b[e] - (float)hk) * 2048.0f);
    }
    *(half8*)(qhi + dst) = qh;
    *(half8*)(qlo + dst) = ql;
    *(half8*)(khi + dst) = kh;
    *(half8*)(klo + dst) = kl;
}

// ---------------------------------------------------------------------------
// Kernel 1 (v3): L = (1/64) * sum_{h,d} q.k via f16x3 MFMA (16x16x32_f16).
// Counted-vmcnt pipeline (T4): raw s_barrier + s_waitcnt vmcnt(8) -- the
// next tile's 8 global_load_lds stay in flight ACROSS every barrier; the
// main loop never drains vmcnt to 0. 16 steps (8 heads x 2 k-blocks),
// double-buffered 64KB LDS (2 blocks/CU). Staging is 8 x 1KB fully
// coalesced per wave per step (k-blocked global layout, linear LDS).
// Frag ds_read_b128 at row*32+quad*8: 8 lanes per 16B bank-group ->
// conflict-free. Accumulation order identical to the absmax-0.0 v1.
// ---------------------------------------------------------------------------
__global__ __launch_bounds__(256, 2) void gemm_f16x3(const half_t* __restrict__ qhi,
                                                     const half_t* __restrict__ qlo,
                                                     const half_t* __restrict__ khi,
                                                     const half_t* __restrict__ klo,
                                                     float* __restrict__ L) {
    const int b  = blockIdx.z;
    const int i0 = blockIdx.y * 128;
    const int j0 = blockIdx.x * 128;
    const int tid  = threadIdx.x;
    const int wave = __builtin_amdgcn_readfirstlane(tid >> 6);
    const int lane = tid & 63;
    const int wr = wave >> 1, wc = wave & 1;
    const int lm = lane & 15, quad = lane >> 4;

    // 4 matrices x 2 buffers x (128 rows x 32 halfs = 8KB) = 64 KB
    __shared__ __align__(16) half_t Ah[2][4096];
    __shared__ __align__(16) half_t Al[2][4096];
    __shared__ __align__(16) half_t Bh[2][4096];
    __shared__ __align__(16) half_t Bl[2][4096];

    const half_t* gmat;
    half_t* lmat;
    int rowoff;
    if      (wave == 0) { gmat = qhi; lmat = &Ah[0][0]; rowoff = i0; }
    else if (wave == 1) { gmat = qlo; lmat = &Al[0][0]; rowoff = i0; }
    else if (wave == 2) { gmat = khi; lmat = &Bh[0][0]; rowoff = j0; }
    else                { gmat = klo; lmat = &Bl[0][0]; rowoff = j0; }
    // plane s (= head*2 + kb) stride = NN*32 halfs; tile is contiguous.
    const half_t* glane0 = gmat + (((size_t)(b * HH) * 2) * NN + rowoff) * 32 + lane * 8;

#define STAGE(sv, bufv)                                                       \
    {                                                                         \
        const half_t* gs = glane0 + (size_t)(sv) * (NN * 32);                 \
        half_t* ls = lmat + (bufv) * 4096;                                    \
        _Pragma("unroll") for (int i = 0; i < 8; ++i)                         \
            gl_lds16(gs + i * 512, ls + i * 512);                             \
    }

#define LOADFRAG(bufv)                                                       \
    _Pragma("unroll") for (int t = 0; t < 4; ++t) {                          \
        const int am = wr * 64 + t * 16 + lm;                                \
        const int bm = wc * 64 + t * 16 + lm;                                \
        fah[t] = *(const half8*)&Ah[bufv][am * 32 + quad * 8];               \
        fal[t] = *(const half8*)&Al[bufv][am * 32 + quad * 8];               \
        fbh[t] = *(const half8*)&Bh[bufv][bm * 32 + quad * 8];               \
        fbl[t] = *(const half8*)&Bl[bufv][bm * 32 + quad * 8];               \
    }

#define MFMAS                                                                 \
    {                                                                         \
        __builtin_amdgcn_s_setprio(1);                                        \
        _Pragma("unroll") for (int tr = 0; tr < 4; ++tr)                      \
            _Pragma("unroll") for (int tc = 0; tc < 4; ++tc) {                \
                acc1[tr][tc] = __builtin_amdgcn_mfma_f32_16x16x32_f16(        \
                    fah[tr], fbh[tc], acc1[tr][tc], 0, 0, 0);                 \
                acc2[tr][tc] = __builtin_amdgcn_mfma_f32_16x16x32_f16(        \
                    fah[tr], fbl[tc], acc2[tr][tc], 0, 0, 0);                 \
                acc2[tr][tc] = __builtin_amdgcn_mfma_f32_16x16x32_f16(        \
                    fal[tr], fbh[tc], acc2[tr][tc], 0, 0, 0);                 \
            }                                                                 \
        __builtin_amdgcn_s_setprio(0);                                        \
    }

#define WAITL0 { asm volatile("s_waitcnt lgkmcnt(0)" ::: "memory");           \
                 __builtin_amdgcn_sched_barrier(0); }
#define WAITV8 { asm volatile("s_waitcnt vmcnt(8)" ::: "memory");             \
                 __builtin_amdgcn_sched_barrier(0); }
#define WAITV0 { asm volatile("s_waitcnt vmcnt(0)" ::: "memory");             \
                 __builtin_amdgcn_sched_barrier(0); }
#define BAR    { __builtin_amdgcn_s_barrier();                                \
                 __builtin_amdgcn_sched_barrier(0); }

    floatx4 acc1[4][4], acc2[4][4];
#pragma unroll
    for (int tr = 0; tr < 4; ++tr)
#pragma unroll
        for (int tc = 0; tc < 4; ++tc) {
            acc1[tr][tc] = (floatx4)0.0f;
            acc2[tr][tc] = (floatx4)0.0f;
        }

    half8 fah[4], fal[4], fbh[4], fbl[4];

    // ---- prologue: stage tiles 0 and 1; wait only tile 0 (8 in flight) ----
    STAGE(0, 0);
    STAGE(1, 1);
    WAITV8;
    BAR;

    // ---- main loop: steps 0..13, vmcnt never drained to 0 ----
#pragma unroll 2
    for (int s = 0; s < 14; ++s) {
        const int cur = s & 1;
        LOADFRAG(cur);        // regs <- buf[cur]
        WAITL0;               // this wave's reads complete
        BAR;                  // all waves done reading buf[cur]
        STAGE(s + 2, cur);    // overwrite freed buffer; 8 more loads in flight
        MFMAS;                // compute tile s
        WAITV8;               // tile s+1 landed (tile s+2's 8 still in flight)
        BAR;                  // collective: buf[cur^1] ready
    }
    // ---- step 14 (no stage; drain for the last tile) ----
    LOADFRAG(0);
    WAITL0;
    BAR;
    MFMAS;
    WAITV0;
    BAR;
    // ---- step 15 ----
    LOADFRAG(1);
    WAITL0;
    MFMAS;

#undef STAGE
#undef LOADFRAG
#undef MFMAS
#undef WAITL0
#undef WAITV8
#undef WAITV0
#undef BAR

    const float s1 = 0.015625f;
    const float s2 = 0.015625f / 2048.0f;
#pragma unroll
    for (int tr = 0; tr < 4; ++tr)
#pragma unroll
        for (int r = 0; r < 4; ++r) {
            const int grow = i0 + wr * 64 + tr * 16 + quad * 4 + r;
            float* Lp = L + ((size_t)b * NN + grow) * NN + j0 + wc * 64 + lm;
#pragma unroll
            for (int tc = 0; tc < 4; ++tc)
                Lp[tc * 16] = acc1[tr][tc][r] * s1 + acc2[tr][tc][r] * s2;
        }
}

// ---------------------------------------------------------------------------
// Kernel 2: one wave per row (unchanged — passed with absmax 0.0).
// ---------------------------------------------------------------------------
__device__ __forceinline__ unsigned long long flip64(double x) {
    unsigned long long v = (unsigned long long)__double_as_longlong(x);
    return v ^ ((0ULL - (v >> 63)) | 0x8000000000000000ULL);
}
__device__ __forceinline__ double unflip64(unsigned long long k) {
    unsigned long long v = (k >> 63) ? (k ^ 0x8000000000000000ULL) : ~k;
    return __longlong_as_double((long long)v);
}

__global__ __launch_bounds__(64) void topk_mask(float* __restrict__ LM,
                                                const float* __restrict__ u) {
    const int row  = blockIdx.x;
    const int lane = threadIdx.x;          // 0..63, one wave
    float* lrow = LM + (size_t)row * NN;
    const float* urow = u + (size_t)row * NN;

    __shared__ int s_idx[64];

    // ---- phase A: stream row, keep only z + hard bitmask ----
    float z[32];
    unsigned hard = 0;
    float4 lb = *(const float4*)(lrow + lane * 4);
    float4 ub = *(const float4*)(urow + lane * 4);
#pragma unroll
    for (int e = 0; e < 8; ++e) {
        float4 lnx, unx;
        if (e < 7) {
            lnx = *(const float4*)(lrow + (e + 1) * 256 + lane * 4);
            unx = *(const float4*)(urow + (e + 1) * 256 + lane * 4);
        }
        const float* ls = (const float*)&lb;
        const float* us = (const float*)&ub;
#pragma unroll
        for (int s = 0; s < 4; ++s) {
            float w = -__logf(us[s] + 1e-9f);
            z[e * 4 + s] = ls[s] - __logf(w + 1e-9f);
            hard |= (us[s] > 0.999f ? 1u : 0u) << (e * 4 + s);
        }
        lb = lnx; ub = unx;
    }

    // ---- phase B: cutoff = (16th largest of 64 lane-maxima) - margin ----
    float v = z[0];
#pragma unroll
    for (int r = 1; r < 32; ++r) v = fmaxf(v, z[r]);
#pragma unroll
    for (int kS = 2; kS <= 64; kS <<= 1) {
#pragma unroll
        for (int j = kS >> 1; j > 0; j >>= 1) {
            float o = __shfl_xor(v, j, 64);
            bool asc = ((lane & kS) == 0);
            bool lower = ((lane & j) == 0);
            float mn = fminf(v, o), mx = fmaxf(v, o);
            v = (asc == lower) ? mn : mx;
        }
    }
    const float cut = __shfl(v, 48, 64) - CUT_MARGIN;

    // ---- phase C: ballot-prefix candidate gather (indices only) ----
    int c = 0;
#pragma unroll
    for (int r = 0; r < 32; ++r) {
        bool p = (z[r] >= cut);
        unsigned long long m = __ballot(p);
        if (p) {
            int slot = c + __popcll(m & ((1ULL << lane) - 1ULL));
            if (slot < 64) s_idx[slot] = (r >> 2) * 256 + lane * 4 + (r & 3);
        }
        c += __popcll(m);
    }
    if (c > 64) c = 64;

    // ---- phase D: f64 keys; fixed 64-wide bitonic sort (ascending);
    //      threshold = sorted lane c-16 (exact 16th-largest z64) ----
    unsigned long long key = 0xFFFFFFFFFFFFFFFFULL;
    if (lane < c) {
        int idx = s_idx[lane];
        double uu = (double)urow[idx] + 1e-9;   // cache-hot gather
        double w  = -log(uu);
        double g  = -log(w + 1e-9);
        key = flip64((double)lrow[idx] + g);
    }
#pragma unroll
    for (int kS = 2; kS <= 64; kS <<= 1) {
#pragma unroll
        for (int j = kS >> 1; j > 0; j >>= 1) {
            unsigned long long o = __shfl_xor(key, j, 64);
            bool asc = ((lane & kS) == 0);
            bool lower = ((lane & j) == 0);
            unsigned long long mn = (key < o) ? key : o;
            unsigned long long mx = (key < o) ? o : key;
            key = (asc == lower) ? mn : mx;
        }
    }
    const double thresh = unflip64(__shfl(key, c - KTOP, 64));

    // ---- phase E0: band|hard elements resolved in f64 ONCE, patch z ----
    const float t_hi = (float)thresh + 3e-4f;
    const float t_lo = (float)thresh - 3e-4f;
    unsigned bm = hard;
#pragma unroll
    for (int r = 0; r < 32; ++r)
        bm |= ((z[r] <= t_hi && z[r] >= t_lo) ? 1u : 0u) << r;
    while (bm) {           // expected ~0-2 iterations per wave, sparse exec
        int t = __builtin_ctz(bm);
        bm &= bm - 1;
        const int idx = (t >> 2) * 256 + lane * 4 + (t & 3);
        double uu = (double)urow[idx] + 1e-9;
        double w  = -log(uu);
        double g  = -log(w + 1e-9);
        double z64 = (double)lrow[idx] + g;    // L still intact (no stores yet)
        z[t] = (z64 >= thresh) ? 1.0e30f : -1.0e30f;
    }

    // ---- phase E1: pure-f32 store pass ----
#pragma unroll
    for (int e = 0; e < 8; ++e) {
        float o[4];
#pragma unroll
        for (int s = 0; s < 4; ++s)
            o[s] = (z[e * 4 + s] > t_hi) ? 1.0f : 0.0f;
        *(float4*)(lrow + e * 256 + lane * 4) = *(float4*)o;
    }
}

extern "C" void kernel_launch(void* const* d_in, const int* in_sizes, int n_in,
                              void* d_out, int out_size, void* d_ws, size_t ws_size,
                              hipStream_t stream) {
    const float* q = (const float*)d_in[0];
    const float* k = (const float*)d_in[1];
    const float* u = (const float*)d_in[2];
    float* out = (float*)d_out;          // logits scratch, then final mask
    const size_t NQ = (size_t)BB * HH * NN * DD;   // 4M elements
    half_t* qhi = (half_t*)d_ws;
    half_t* qlo = qhi + NQ;
    half_t* khi = qlo + NQ;
    half_t* klo = khi + NQ;              // 32 MB total in d_ws

    split_kblock<<<(int)(NQ / 8 / 256), 256, 0, stream>>>(q, k, qhi, qlo, khi, klo);

    dim3 grid1(NN / 128, NN / 128, BB);
    gemm_f16x3<<<grid1, 256, 0, stream>>>(qhi, qlo, khi, klo, out);

    topk_mask<<<BB * NN, 64, 0, stream>>>(out, u);
}

// Round 4
// 218.314 us; speedup vs baseline: 1.0708x; 1.0148x over previous
//
#include <hip/hip_runtime.h>
#include <math.h>

#define BB 4
#define HH 8
#define NN 2048
#define DD 64
#define KTOP 16
#define CUT_MARGIN 1e-3f

typedef _Float16 half_t;
typedef __attribute__((ext_vector_type(8))) _Float16 half8;
typedef __attribute__((ext_vector_type(4))) float floatx4;

// async 16B global->LDS copy (hardware scatters lane i at ldsbase + i*16)
__device__ __forceinline__ void gl_lds16(const half_t* g, half_t* l) {
    __builtin_amdgcn_global_load_lds(
        (const __attribute__((address_space(1))) void*)g,
        (__attribute__((address_space(3))) void*)l, 16, 0, 0);
}

// ---------------------------------------------------------------------------
// Kernel 0: split fp32 q,k into f16 hi + f16 (lo*2^11).
// Layout: per (b,h,kb) plane (kb = d/32), 16 tiles of 128 rows; each 8KB
// tile stored PRE-SWIZZLED in phys-unit order p(r,kg) = (r>>3)*32 + kg*8
// + (r&7)  (16B units; kg = (d>>3)&3). Gemm then stages identity-linear
// (fully coalesced) and reads conflict-free (v2-verified pattern).
// ---------------------------------------------------------------------------
__global__ __launch_bounds__(256) void split_swz(const float* __restrict__ q,
                                                 const float* __restrict__ kk,
                                                 half_t* __restrict__ qhi,
                                                 half_t* __restrict__ qlo,
                                                 half_t* __restrict__ khi,
                                                 half_t* __restrict__ klo) {
    const int uidx = blockIdx.x * 256 + threadIdx.x;  // 16B-unit index
    const size_t src = (size_t)uidx * 8;
    const int R   = uidx >> 3;          // global row over B*H*N
    const int kg8 = uidx & 7;           // which 8-float group (d = kg8*8..+7)
    const int bh  = R >> 11;            // b*H + h   (N = 2048)
    const int n   = R & 2047;
    const int kb  = kg8 >> 2;           // k-block (d>>5)
    const int kgw = kg8 & 3;            // 8-group within k-block
    const int tile = n >> 7;
    const int r    = n & 127;
    const int p    = ((r >> 3) << 5) + (kgw << 3) + (r & 7);
    const size_t dst = (((size_t)(bh * 2 + kb) * 16 + tile) * 512 + p) * 8;

    float a[8], b[8];
    *(float4*)&a[0] = *(const float4*)(q + src);
    *(float4*)&a[4] = *(const float4*)(q + src + 4);
    *(float4*)&b[0] = *(const float4*)(kk + src);
    *(float4*)&b[4] = *(const float4*)(kk + src + 4);
    half8 qh, ql, kh, kl;
#pragma unroll
    for (int e = 0; e < 8; ++e) {
        half_t hq = (half_t)a[e];
        half_t hk = (half_t)b[e];
        qh[e] = hq; ql[e] = (half_t)((a[e] - (float)hq) * 2048.0f);
        kh[e] = hk; kl[e] = (half_t)((b[e] - (float)hk) * 2048.0f);
    }
    *(half8*)(qhi + dst) = qh;
    *(half8*)(qlo + dst) = ql;
    *(half8*)(khi + dst) = kh;
    *(half8*)(klo + dst) = kl;
}

// ---------------------------------------------------------------------------
// Kernel 1 (v4): L = (1/64) * sum_{h,d} q.k via f16x3 MFMA (16x16x32_f16).
// v3's counted-vmcnt pipeline (vmcnt(8) across barriers, never drained in
// the main loop) + v1's pre-swizzled global so staging is identity-linear
// (8 x 1KB contiguous per wave per step) AND frag reads are conflict-free
// (byte-off mod 128 = (am&7)*16 -> 8 slots x 2 lanes, free).
// Accumulation order identical to the absmax-0.0 v1/v3.
// ---------------------------------------------------------------------------
__global__ __launch_bounds__(256, 2) void gemm_f16x3(const half_t* __restrict__ qhi,
                                                     const half_t* __restrict__ qlo,
                                                     const half_t* __restrict__ khi,
                                                     const half_t* __restrict__ klo,
                                                     float* __restrict__ L) {
    const int b  = blockIdx.z;
    const int i0 = blockIdx.y * 128;
    const int j0 = blockIdx.x * 128;
    const int tid  = threadIdx.x;
    const int wave = __builtin_amdgcn_readfirstlane(tid >> 6);
    const int lane = tid & 63;
    const int wr = wave >> 1, wc = wave & 1;
    const int lm = lane & 15, quad = lane >> 4;

    // 4 matrices x 2 buffers x 8KB = 64 KB  (2 blocks/CU)
    __shared__ __align__(16) half_t Ah[2][4096];
    __shared__ __align__(16) half_t Al[2][4096];
    __shared__ __align__(16) half_t Bh[2][4096];
    __shared__ __align__(16) half_t Bl[2][4096];

    const half_t* gmat;
    half_t* lmat;
    int tileoff;
    if      (wave == 0) { gmat = qhi; lmat = &Ah[0][0]; tileoff = (i0 >> 7) * 4096; }
    else if (wave == 1) { gmat = qlo; lmat = &Al[0][0]; tileoff = (i0 >> 7) * 4096; }
    else if (wave == 2) { gmat = khi; lmat = &Bh[0][0]; tileoff = (j0 >> 7) * 4096; }
    else                { gmat = klo; lmat = &Bl[0][0]; tileoff = (j0 >> 7) * 4096; }
    // plane s (= head*2 + kb) stride = NN*32 = 65536 halfs; tile contiguous.
    const half_t* glane0 = gmat + (size_t)(b * 16) * 65536 + tileoff + lane * 8;

#define STAGE(sv, bufv)                                                       \
    {                                                                         \
        const half_t* gs = glane0 + (size_t)(sv) * 65536;                     \
        half_t* ls = lmat + (bufv) * 4096;                                    \
        _Pragma("unroll") for (int i = 0; i < 8; ++i)                         \
            gl_lds16(gs + i * 512, ls + i * 512);                             \
    }

#define LOADFRAG(bufv)                                                        \
    _Pragma("unroll") for (int t = 0; t < 4; ++t) {                           \
        const int am = wr * 64 + t * 16 + lm;                                 \
        const int bm = wc * 64 + t * 16 + lm;                                 \
        const int ai = ((am >> 3) << 8) + (quad << 6) + ((am & 7) << 3);      \
        const int bi = ((bm >> 3) << 8) + (quad << 6) + ((bm & 7) << 3);      \
        fah[t] = *(const half8*)&Ah[bufv][ai];                                \
        fal[t] = *(const half8*)&Al[bufv][ai];                                \
        fbh[t] = *(const half8*)&Bh[bufv][bi];                                \
        fbl[t] = *(const half8*)&Bl[bufv][bi];                                \
    }

#define MFMAS                                                                 \
    {                                                                         \
        __builtin_amdgcn_s_setprio(1);                                        \
        _Pragma("unroll") for (int tr = 0; tr < 4; ++tr)                      \
            _Pragma("unroll") for (int tc = 0; tc < 4; ++tc) {                \
                acc1[tr][tc] = __builtin_amdgcn_mfma_f32_16x16x32_f16(        \
                    fah[tr], fbh[tc], acc1[tr][tc], 0, 0, 0);                 \
                acc2[tr][tc] = __builtin_amdgcn_mfma_f32_16x16x32_f16(        \
                    fah[tr], fbl[tc], acc2[tr][tc], 0, 0, 0);                 \
                acc2[tr][tc] = __builtin_amdgcn_mfma_f32_16x16x32_f16(        \
                    fal[tr], fbh[tc], acc2[tr][tc], 0, 0, 0);                 \
            }                                                                 \
        __builtin_amdgcn_s_setprio(0);                                        \
    }

#define WAITL0 { asm volatile("s_waitcnt lgkmcnt(0)" ::: "memory");           \
                 __builtin_amdgcn_sched_barrier(0); }
#define WAITV8 { asm volatile("s_waitcnt vmcnt(8)" ::: "memory");             \
                 __builtin_amdgcn_sched_barrier(0); }
#define WAITV0 { asm volatile("s_waitcnt vmcnt(0)" ::: "memory");             \
                 __builtin_amdgcn_sched_barrier(0); }
#define BAR    { __builtin_amdgcn_s_barrier();                                \
                 __builtin_amdgcn_sched_barrier(0); }

    floatx4 acc1[4][4], acc2[4][4];
#pragma unroll
    for (int tr = 0; tr < 4; ++tr)
#pragma unroll
        for (int tc = 0; tc < 4; ++tc) {
            acc1[tr][tc] = (floatx4)0.0f;
            acc2[tr][tc] = (floatx4)0.0f;
        }

    half8 fah[4], fal[4], fbh[4], fbl[4];

    // ---- prologue: stage tiles 0 and 1; wait only tile 0 (8 in flight) ----
    STAGE(0, 0);
    STAGE(1, 1);
    WAITV8;
    BAR;

    // ---- main loop: steps 0..13, vmcnt never drained to 0 ----
#pragma unroll 2
    for (int s = 0; s < 14; ++s) {
        const int cur = s & 1;
        LOADFRAG(cur);        // regs <- buf[cur]
        WAITL0;               // this wave's reads complete
        BAR;                  // all waves done reading buf[cur]
        STAGE(s + 2, cur);    // overwrite freed buffer; 8 more loads in flight
        MFMAS;                // compute tile s
        WAITV8;               // tile s+1 landed (tile s+2's 8 still in flight)
        BAR;                  // collective: buf[cur^1] ready
    }
    // ---- step 14 (no stage; drain for the last tile) ----
    LOADFRAG(0);
    WAITL0;
    BAR;
    MFMAS;
    WAITV0;
    BAR;
    // ---- step 15 ----
    LOADFRAG(1);
    WAITL0;
    MFMAS;

#undef STAGE
#undef LOADFRAG
#undef MFMAS
#undef WAITL0
#undef WAITV8
#undef WAITV0
#undef BAR

    const float s1 = 0.015625f;
    const float s2 = 0.015625f / 2048.0f;
#pragma unroll
    for (int tr = 0; tr < 4; ++tr)
#pragma unroll
        for (int r = 0; r < 4; ++r) {
            const int grow = i0 + wr * 64 + tr * 16 + quad * 4 + r;
            float* Lp = L + ((size_t)b * NN + grow) * NN + j0 + wc * 64 + lm;
#pragma unroll
            for (int tc = 0; tc < 4; ++tc)
                Lp[tc * 16] = acc1[tr][tc][r] * s1 + acc2[tr][tc][r] * s2;
        }
}

// ---------------------------------------------------------------------------
// Kernel 2 (v2): 4 independent rows per 256-thread block (one wave each) --
// same wave-local algorithm (passed, absmax 0.0), better CU packing than
// 64-thread blocks (workgroup-slot limit was capping occupancy).
// ---------------------------------------------------------------------------
__device__ __forceinline__ unsigned long long flip64(double x) {
    unsigned long long v = (unsigned long long)__double_as_longlong(x);
    return v ^ ((0ULL - (v >> 63)) | 0x8000000000000000ULL);
}
__device__ __forceinline__ double unflip64(unsigned long long k) {
    unsigned long long v = (k >> 63) ? (k ^ 0x8000000000000000ULL) : ~k;
    return __longlong_as_double((long long)v);
}

__global__ __launch_bounds__(256) void topk_mask(float* __restrict__ LM,
                                                 const float* __restrict__ u) {
    const int wave = threadIdx.x >> 6;     // 0..3 (independent rows)
    const int lane = threadIdx.x & 63;     // 0..63, one wave
    const int row  = blockIdx.x * 4 + wave;
    float* lrow = LM + (size_t)row * NN;
    const float* urow = u + (size_t)row * NN;

    __shared__ int s_idx[4][64];

    // ---- phase A: stream row, keep only z + hard bitmask ----
    float z[32];
    unsigned hard = 0;
    float4 lb = *(const float4*)(lrow + lane * 4);
    float4 ub = *(const float4*)(urow + lane * 4);
#pragma unroll
    for (int e = 0; e < 8; ++e) {
        float4 lnx, unx;
        if (e < 7) {
            lnx = *(const float4*)(lrow + (e + 1) * 256 + lane * 4);
            unx = *(const float4*)(urow + (e + 1) * 256 + lane * 4);
        }
        const float* ls = (const float*)&lb;
        const float* us = (const float*)&ub;
#pragma unroll
        for (int s = 0; s < 4; ++s) {
            float w = -__logf(us[s] + 1e-9f);
            z[e * 4 + s] = ls[s] - __logf(w + 1e-9f);
            hard |= (us[s] > 0.999f ? 1u : 0u) << (e * 4 + s);
        }
        lb = lnx; ub = unx;
    }

    // ---- phase B: cutoff = (16th largest of 64 lane-maxima) - margin ----
    float v = z[0];
#pragma unroll
    for (int r = 1; r < 32; ++r) v = fmaxf(v, z[r]);
#pragma unroll
    for (int kS = 2; kS <= 64; kS <<= 1) {
#pragma unroll
        for (int j = kS >> 1; j > 0; j >>= 1) {
            float o = __shfl_xor(v, j, 64);
            bool asc = ((lane & kS) == 0);
            bool lower = ((lane & j) == 0);
            float mn = fminf(v, o), mx = fmaxf(v, o);
            v = (asc == lower) ? mn : mx;
        }
    }
    const float cut = __shfl(v, 48, 64) - CUT_MARGIN;

    // ---- phase C: ballot-prefix candidate gather (indices only) ----
    int c = 0;
#pragma unroll
    for (int r = 0; r < 32; ++r) {
        bool p = (z[r] >= cut);
        unsigned long long m = __ballot(p);
        if (p) {
            int slot = c + __popcll(m & ((1ULL << lane) - 1ULL));
            if (slot < 64) s_idx[wave][slot] = (r >> 2) * 256 + lane * 4 + (r & 3);
        }
        c += __popcll(m);
    }
    if (c > 64) c = 64;

    // ---- phase D: f64 keys; fixed 64-wide bitonic sort (ascending);
    //      threshold = sorted lane c-16 (exact 16th-largest z64) ----
    unsigned long long key = 0xFFFFFFFFFFFFFFFFULL;
    if (lane < c) {
        int idx = s_idx[wave][lane];
        double uu = (double)urow[idx] + 1e-9;   // cache-hot gather
        double w  = -log(uu);
        double g  = -log(w + 1e-9);
        key = flip64((double)lrow[idx] + g);
    }
#pragma unroll
    for (int kS = 2; kS <= 64; kS <<= 1) {
#pragma unroll
        for (int j = kS >> 1; j > 0; j >>= 1) {
            unsigned long long o = __shfl_xor(key, j, 64);
            bool asc = ((lane & kS) == 0);
            bool lower = ((lane & j) == 0);
            unsigned long long mn = (key < o) ? key : o;
            unsigned long long mx = (key < o) ? o : key;
            key = (asc == lower) ? mn : mx;
        }
    }
    const double thresh = unflip64(__shfl(key, c - KTOP, 64));

    // ---- phase E0: band|hard elements resolved in f64 ONCE, patch z ----
    const float t_hi = (float)thresh + 3e-4f;
    const float t_lo = (float)thresh - 3e-4f;
    unsigned bm = hard;
#pragma unroll
    for (int r = 0; r < 32; ++r)
        bm |= ((z[r] <= t_hi && z[r] >= t_lo) ? 1u : 0u) << r;
    while (bm) {           // expected ~0-2 iterations per wave, sparse exec
        int t = __builtin_ctz(bm);
        bm &= bm - 1;
        const int idx = (t >> 2) * 256 + lane * 4 + (t & 3);
        double uu = (double)urow[idx] + 1e-9;
        double w  = -log(uu);
        double g  = -log(w + 1e-9);
        double z64 = (double)lrow[idx] + g;    // L still intact (no stores yet)
        z[t] = (z64 >= thresh) ? 1.0e30f : -1.0e30f;
    }

    // ---- phase E1: pure-f32 store pass ----
#pragma unroll
    for (int e = 0; e < 8; ++e) {
        float o[4];
#pragma unroll
        for (int s = 0; s < 4; ++s)
            o[s] = (z[e * 4 + s] > t_hi) ? 1.0f : 0.0f;
        *(float4*)(lrow + e * 256 + lane * 4) = *(float4*)o;
    }
}

extern "C" void kernel_launch(void* const* d_in, const int* in_sizes, int n_in,
                              void* d_out, int out_size, void* d_ws, size_t ws_size,
                              hipStream_t stream) {
    const float* q = (const float*)d_in[0];
    const float* k = (const float*)d_in[1];
    const float* u = (const float*)d_in[2];
    float* out = (float*)d_out;          // logits scratch, then final mask
    const size_t NQ = (size_t)BB * HH * NN * DD;   // 4M elements
    half_t* qhi = (half_t*)d_ws;
    half_t* qlo = qhi + NQ;
    half_t* khi = qlo + NQ;
    half_t* klo = khi + NQ;              // 32 MB total in d_ws

    split_swz<<<(int)(NQ / 8 / 256), 256, 0, stream>>>(q, k, qhi, qlo, khi, klo);

    dim3 grid1(NN / 128, NN / 128, BB);
    gemm_f16x3<<<grid1, 256, 0, stream>>>(qhi, qlo, khi, klo, out);

    topk_mask<<<BB * NN / 4, 256, 0, stream>>>(out, u);
}